// Round 2
// baseline (338.773 us; speedup 1.0000x reference)
//
#include <hip/hip_runtime.h>

// CenterLoss: mean((input_x - target_x[labels])^2)
// N=131072 rows, FEAT=512, NCLASS=1000. All f32. Output: single f32 scalar.
//
// Memory-bound: 256 MiB input_x read dominates. Strategy:
//  - float4 (16B) coalesced loads, grid-stride over 16.7M float4 chunks
//  - nontemporal loads for x (streamed once) so the 2 MiB center table
//    stays cache-hot (gathered 131x per center on average)
//  - 128 chunks/row -> each wave covers <=2 rows: label load + center gather
//    are wave-near-uniform; centers L2-hot
//  - deterministic 2-kernel reduction: block partials (f32) -> d_ws,
//    final 1-block reduce in double -> d_out[0]

#define NROWS   131072
#define FEAT    512
#define NCLASS  1000
#define CHUNKS_PER_ROW (FEAT / 4)            // 128
#define TOTAL_CHUNKS   ((long long)NROWS * CHUNKS_PER_ROW)  // 16,777,216

typedef float f32x4 __attribute__((ext_vector_type(4)));

constexpr int BLOCKS  = 2048;   // 8 blocks/CU on 256 CUs
constexpr int THREADS = 256;

__global__ __launch_bounds__(THREADS) void center_loss_partial(
        const f32x4* __restrict__ x,         // [NROWS * 128]
        const int*   __restrict__ labels,    // [NROWS]
        const f32x4* __restrict__ centers,   // [NCLASS * 128]
        float*       __restrict__ partial)   // [BLOCKS]
{
    const int tid = threadIdx.x;
    long long g      = (long long)blockIdx.x * THREADS + tid;
    const long long stride = (long long)gridDim.x * THREADS;

    float acc = 0.0f;
    for (long long c = g; c < TOTAL_CHUNKS; c += stride) {
        const int row = (int)(c >> 7);       // c / 128
        const int col = (int)(c & 127);      // c % 128
        const int lab = labels[row];         // wave-near-uniform, cache-hot
        const f32x4 xv = __builtin_nontemporal_load(&x[c]);   // streamed, no reuse
        const f32x4 cv = centers[lab * CHUNKS_PER_ROW + col]; // cached, reused
        const float dx = xv.x - cv.x;
        const float dy = xv.y - cv.y;
        const float dz = xv.z - cv.z;
        const float dw = xv.w - cv.w;
        acc += dx * dx + dy * dy + dz * dz + dw * dw;
    }

    // wave (64-lane) butterfly reduce
    for (int off = 32; off > 0; off >>= 1)
        acc += __shfl_down(acc, off, 64);

    __shared__ float s[THREADS / 64];
    const int lane = tid & 63;
    const int wave = tid >> 6;
    if (lane == 0) s[wave] = acc;
    __syncthreads();
    if (tid == 0)
        partial[blockIdx.x] = s[0] + s[1] + s[2] + s[3];
}

__global__ __launch_bounds__(256) void center_loss_final(
        const float* __restrict__ partial,   // [BLOCKS]
        float*       __restrict__ out)       // [1]
{
    const int tid = threadIdx.x;
    double acc = 0.0;
    for (int i = tid; i < BLOCKS; i += 256)
        acc += (double)partial[i];

    for (int off = 32; off > 0; off >>= 1)
        acc += __shfl_down(acc, off, 64);

    __shared__ double s[4];
    const int lane = tid & 63;
    const int wave = tid >> 6;
    if (lane == 0) s[wave] = acc;
    __syncthreads();
    if (tid == 0) {
        const double total = s[0] + s[1] + s[2] + s[3];
        out[0] = (float)(total / ((double)NROWS * (double)FEAT));
    }
}

extern "C" void kernel_launch(void* const* d_in, const int* in_sizes, int n_in,
                              void* d_out, int out_size, void* d_ws, size_t ws_size,
                              hipStream_t stream) {
    const f32x4* x       = (const f32x4*)d_in[0];  // input_x  [131072,512] f32
    const int*   labels  = (const int*)  d_in[1];  // labels   [131072] i32
    const f32x4* centers = (const f32x4*)d_in[2];  // target_x [1000,512] f32
    float*       out     = (float*)d_out;
    float*       partial = (float*)d_ws;           // BLOCKS floats (8 KiB)

    center_loss_partial<<<BLOCKS, THREADS, 0, stream>>>(x, labels, centers, partial);
    center_loss_final<<<1, 256, 0, stream>>>(partial, out);
}